// Round 2
// baseline (251.999 us; speedup 1.0000x reference)
//
#include <hip/hip_runtime.h>
#include <stdint.h>

// DETR PartMap: [2, B, Q, H, W] outside-box masks (1.0 outside, 0.0 inside).
// B=64, Q=300, H=W=40. Output 61.44M fp32 = 245.8 MB -> pure write-BW-bound.
//
// Fused single kernel: each block owns 16 (s,b,q) maps. Threads 0..15 compute
// the 16 box descriptors (40-bit x-outside bitmask + y1/y2) into LDS; then all
// 256 threads stream the 16 maps' 6400 float4 (25 iterations x 256 x 16 B)
// with incremental index math (no per-store division by 400), LDS-broadcast
// descriptor reads, and non-temporal dwordx4 stores (output is never re-read;
// don't dirty L2).

#define B_ 64
#define Q_ 300
#define HM 40
#define WM 40
#define NBOX (2 * B_ * Q_)                   // 38,400 maps
#define MAPS_PER_BLOCK 16
#define NBLOCKS (NBOX / MAPS_PER_BLOCK)      // 2,400
#define F4_PER_MAP 400                       // 40*40/4
#define ITERS ((MAPS_PER_BLOCK * F4_PER_MAP) / 256)   // 25

// clang-native 4-float vector: __builtin_nontemporal_store requires a
// scalar/vector type, not HIP's HIP_vector_type class.
typedef float vfloat4 __attribute__((ext_vector_type(4)));

__global__ __launch_bounds__(256) void partmap_fused_kernel(
    const float* __restrict__ obj,
    const float* __restrict__ sub,
    const int*   __restrict__ img,     // [B,2] = (h, w) int32
    vfloat4*     __restrict__ out)
{
    __shared__ uint32_t s_d0[MAPS_PER_BLOCK];
    __shared__ uint32_t s_d1[MAPS_PER_BLOCK];

    const int tid = threadIdx.x;

    // ---- phase 1: 16 threads compute 16 box descriptors into LDS ----
    if (tid < MAPS_PER_BLOCK) {
        #pragma clang fp contract(off)
        int id = blockIdx.x * MAPS_PER_BLOCK + tid;   // (s*64 + b)*300 + q
        int q  = id % Q_;
        int sb = id / Q_;
        int b  = sb & 63;
        int s  = sb >> 6;

        const float* coord = s ? sub : obj;
        float4 c = ((const float4*)coord)[b * Q_ + q];   // (cx, cy, w, h)

        float sh = (float)img[b * 2 + 0];
        float sw = (float)img[b * 2 + 1];

        // Exact numpy op order: (cx - 0.5*w) * sw / 32, floor, cast. No contraction.
        float x1f = (c.x - 0.5f * c.z) * sw / 32.0f;
        float y1f = (c.y - 0.5f * c.w) * sh / 32.0f;
        float x2f = (c.x + 0.5f * c.z) * sw / 32.0f;
        float y2f = (c.y + 0.5f * c.w) * sh / 32.0f;

        int x1 = (int)floorf(x1f);                // can be negative (>= -20)
        int y1 = (int)floorf(y1f);
        int x2 = min((int)floorf(x2f), WM - 1);   // in [0,39]
        int y2 = min((int)floorf(y2f), HM - 1);   // in [0,39]

        // inside-x bits [x1 .. x2] within 40 bits; outside = complement.
        uint64_t lo = (x1 <= 0) ? ~0ull : ~((1ull << x1) - 1ull);   // x1 <= 39
        uint64_t hi = (1ull << (x2 + 1)) - 1ull;                    // x2 in [0,39]
        uint64_t outside = (~(lo & hi)) & ((1ull << 40) - 1ull);

        s_d0[tid] = (uint32_t)outside;
        s_d1[tid] = ((uint32_t)(outside >> 32) & 0xFFu)
                  | (((uint32_t)y1 & 0xFFu) << 8)
                  | (((uint32_t)y2 & 0xFFu) << 16);
    }
    __syncthreads();

    // ---- phase 2: stream 16 maps = 6400 float4 per block ----
    // off = tid + 256*it; lm = off/400; rem = off%400. Maintained incrementally
    // (256 < 400 -> at most one wrap per step). 64 consecutive lanes straddle
    // at most 2 maps -> LDS reads are broadcast, conflict-free.
    int rem = tid;     // tid < 400
    int lm  = 0;
    vfloat4* __restrict__ p = out + (size_t)blockIdx.x * (MAPS_PER_BLOCK * F4_PER_MAP) + tid;

    for (int it = 0; it < ITERS; ++it) {
        uint32_t d0 = s_d0[lm];
        uint32_t d1 = s_d1[lm];

        int h  = rem / 10;                 // rem < 400, magic-mul
        int w0 = (rem - h * 10) * 4;       // bit shift for this float4's 4 cols

        int y1 = (int)(int8_t)(d1 >> 8);
        int y2 = (int)(int8_t)(d1 >> 16);

        // all-ones if h outside [y1,y2]: sign bit of (h-y1)|(y2-h)
        int rneg = ((h - y1) | (y2 - h)) >> 31;

        // funnel-shift the 40-bit x-outside mask down by w0; bits 0..3 are the
        // 4 elements of this float4 (y1/y2 bytes in d1 land at bits >= 4).
        uint32_t m = (uint32_t)((((uint64_t)d1 << 32) | d0) >> w0) | (uint32_t)rneg;

        vfloat4 r;
        r.x = (float)( m        & 1u);
        r.y = (float)((m >> 1)  & 1u);
        r.z = (float)((m >> 2)  & 1u);
        r.w = (float)((m >> 3)  & 1u);

        __builtin_nontemporal_store(r, p);

        rem += 256;
        if (rem >= F4_PER_MAP) { rem -= F4_PER_MAP; ++lm; }
        p += 256;
    }
}

extern "C" void kernel_launch(void* const* d_in, const int* in_sizes, int n_in,
                              void* d_out, int out_size, void* d_ws, size_t ws_size,
                              hipStream_t stream) {
    const float* obj = (const float*)d_in[0];   // [B,Q,4] f32
    const float* sub = (const float*)d_in[1];   // [B,Q,4] f32
    const int*   img = (const int*)d_in[2];     // [B,2] int32 (h, w)
    // d_in[3] = mask (bool) — only its shape is used; ignored.
    (void)d_ws; (void)ws_size;

    partmap_fused_kernel<<<dim3(NBLOCKS), dim3(256), 0, stream>>>(
        obj, sub, img, (vfloat4*)d_out);
}

// Round 3
// 240.434 us; speedup vs baseline: 1.0481x; 1.0481x over previous
//
#include <hip/hip_runtime.h>
#include <stdint.h>

// DETR PartMap: [2, B, Q, H, W] outside-box masks (1.0 outside, 0.0 inside).
// B=64, Q=300, H=W=40. Output 61.44M fp32 = 245.8 MB -> pure write-BW-bound.
//
// Fused single kernel: each block owns 16 (s,b,q) maps. Threads 0..15 compute
// the 16 box descriptors (40-bit x-outside bitmask + y1/y2) into LDS; then all
// 256 threads stream the 16 maps' 6400 float4 (25 iterations x 256 x 16 B)
// with incremental index math, LDS-broadcast descriptor reads, and PLAIN
// dwordx4 stores. NT stores regressed ~5 us in R2 (bypassing L2 defeats
// write-combining; the 6.6 TB/s rocclr fill uses plain stores) -- reverted.

#define B_ 64
#define Q_ 300
#define HM 40
#define WM 40
#define NBOX (2 * B_ * Q_)                   // 38,400 maps
#define MAPS_PER_BLOCK 16
#define NBLOCKS (NBOX / MAPS_PER_BLOCK)      // 2,400
#define F4_PER_MAP 400                       // 40*40/4
#define ITERS ((MAPS_PER_BLOCK * F4_PER_MAP) / 256)   // 25

typedef float vfloat4 __attribute__((ext_vector_type(4)));

__global__ __launch_bounds__(256) void partmap_fused_kernel(
    const float* __restrict__ obj,
    const float* __restrict__ sub,
    const int*   __restrict__ img,     // [B,2] = (h, w) int32
    vfloat4*     __restrict__ out)
{
    __shared__ uint2 s_d[MAPS_PER_BLOCK];   // {xmask_lo, xmask_hi|y1<<8|y2<<16}

    const int tid = threadIdx.x;

    // ---- phase 1: 16 threads compute 16 box descriptors into LDS ----
    if (tid < MAPS_PER_BLOCK) {
        #pragma clang fp contract(off)
        int id = blockIdx.x * MAPS_PER_BLOCK + tid;   // (s*64 + b)*300 + q
        int q  = id % Q_;
        int sb = id / Q_;
        int b  = sb & 63;
        int s  = sb >> 6;

        const float* coord = s ? sub : obj;
        float4 c = ((const float4*)coord)[b * Q_ + q];   // (cx, cy, w, h)

        float sh = (float)img[b * 2 + 0];
        float sw = (float)img[b * 2 + 1];

        // Exact numpy op order: (cx - 0.5*w) * sw / 32, floor, cast. No contraction.
        float x1f = (c.x - 0.5f * c.z) * sw / 32.0f;
        float y1f = (c.y - 0.5f * c.w) * sh / 32.0f;
        float x2f = (c.x + 0.5f * c.z) * sw / 32.0f;
        float y2f = (c.y + 0.5f * c.w) * sh / 32.0f;

        int x1 = (int)floorf(x1f);                // can be negative (>= -20)
        int y1 = (int)floorf(y1f);
        int x2 = min((int)floorf(x2f), WM - 1);   // in [0,39]
        int y2 = min((int)floorf(y2f), HM - 1);   // in [0,39]

        // inside-x bits [x1 .. x2] within 40 bits; outside = complement.
        uint64_t lo = (x1 <= 0) ? ~0ull : ~((1ull << x1) - 1ull);   // x1 <= 39
        uint64_t hi = (1ull << (x2 + 1)) - 1ull;                    // x2 in [0,39]
        uint64_t outside = (~(lo & hi)) & ((1ull << 40) - 1ull);

        uint32_t d0 = (uint32_t)outside;
        uint32_t d1 = ((uint32_t)(outside >> 32) & 0xFFu)
                    | (((uint32_t)y1 & 0xFFu) << 8)
                    | (((uint32_t)y2 & 0xFFu) << 16);
        s_d[tid] = make_uint2(d0, d1);
    }
    __syncthreads();

    // ---- phase 2: stream 16 maps = 6400 float4 per block ----
    // off = tid + 256*it; lm = off/400; rem = off%400. Maintained incrementally
    // (256 < 400 -> at most one wrap per step). 64 consecutive lanes straddle
    // at most 2 maps -> LDS reads are broadcast, conflict-free.
    int rem = tid;     // tid < 400
    int lm  = 0;
    vfloat4* __restrict__ p = out + (size_t)blockIdx.x * (MAPS_PER_BLOCK * F4_PER_MAP) + tid;

    #pragma unroll
    for (int it = 0; it < ITERS; ++it) {
        uint2 d = s_d[lm];                 // single ds_read_b64, broadcast

        int h  = rem / 10;                 // rem < 400, magic-mul
        int w0 = (rem - h * 10) * 4;       // bit shift for this float4's 4 cols

        int y1 = (int)(int8_t)(d.y >> 8);
        int y2 = (int)(int8_t)(d.y >> 16);

        // all-ones if h outside [y1,y2]: sign bit of (h-y1)|(y2-h)
        int rneg = ((h - y1) | (y2 - h)) >> 31;

        // funnel-shift the 40-bit x-outside mask down by w0; bits 0..3 are the
        // 4 elements of this float4 (y1/y2 bytes in d.y land at bits >= 4).
        uint32_t m = (uint32_t)((((uint64_t)d.y << 32) | d.x) >> w0) | (uint32_t)rneg;

        vfloat4 r;
        r.x = (float)( m        & 1u);
        r.y = (float)((m >> 1)  & 1u);
        r.z = (float)((m >> 2)  & 1u);
        r.w = (float)((m >> 3)  & 1u);

        p[0] = r;

        rem += 256;
        if (rem >= F4_PER_MAP) { rem -= F4_PER_MAP; ++lm; }
        p += 256;
    }
}

extern "C" void kernel_launch(void* const* d_in, const int* in_sizes, int n_in,
                              void* d_out, int out_size, void* d_ws, size_t ws_size,
                              hipStream_t stream) {
    const float* obj = (const float*)d_in[0];   // [B,Q,4] f32
    const float* sub = (const float*)d_in[1];   // [B,Q,4] f32
    const int*   img = (const int*)d_in[2];     // [B,2] int32 (h, w)
    // d_in[3] = mask (bool) — only its shape is used; ignored.
    (void)d_ws; (void)ws_size;

    partmap_fused_kernel<<<dim3(NBLOCKS), dim3(256), 0, stream>>>(
        obj, sub, img, (vfloat4*)d_out);
}